// Round 1
// baseline (940.353 us; speedup 1.0000x reference)
//
#include <hip/hip_runtime.h>

#define N_TOK   32768
#define EMB_DIM 1024

// ---- workspace layout (bytes) ----
// [0,16)      counts[4]
// [16,32)     cursors[4]
// [1024, +128KB)  sorted token index list (32768 ints), bucket-contiguous
// [256KB, +3.75MB) W^T bf16 (per-bucket, swizzled)
// [4MB, ...)  gathered emb rows bf16 (bucket-contiguous, rows padded to 128/bucket, swizzled)
#define LIST_OFF 1024u
#define WT_OFF   262144u
#define EBF_OFF  4194304u

typedef __attribute__((ext_vector_type(8))) short short8;
typedef __attribute__((ext_vector_type(4))) float f32x4;

__device__ __forceinline__ int bucket_of(int v) { return (v >= 300) + (v >= 3000) + (v >= 30000); }

__device__ __forceinline__ unsigned short f2bf(float f) {  // round-to-nearest-even fp32->bf16
  unsigned u = __float_as_uint(f);
  return (unsigned short)((u + 0x7FFFu + ((u >> 16) & 1u)) >> 16);
}

__device__ __forceinline__ unsigned wt_base(int b) {
  return b == 0 ? 0u : b == 1 ? 2097152u : b == 2 ? 3145728u : 3670016u;
}

__device__ __forceinline__ void gload_lds16(const void* g, void* l) {
  __builtin_amdgcn_global_load_lds((const __attribute__((address_space(1))) unsigned*)g,
                                   (__attribute__((address_space(3))) unsigned*)l, 16, 0, 0);
}

// ---- phase 1: histogram ----
__global__ void k_count(const int* __restrict__ x, int* __restrict__ wsi) {
  int i = blockIdx.x * 256 + threadIdx.x;           // grid is exact (128*256 == N_TOK)
  atomicAdd(&wsi[bucket_of(x[i])], 1);
}

// ---- phase 2: scatter token ids into bucket-contiguous list ----
__global__ void k_scatter(const int* __restrict__ x, int* __restrict__ wsi) {
  int i = blockIdx.x * 256 + threadIdx.x;
  int v = x[i];
  int b = bucket_of(v);
  int off = 0;
#pragma unroll
  for (int j = 0; j < 3; ++j) if (j < b) off += wsi[j];
  int pos = atomicAdd(&wsi[4 + b], 1);
  wsi[LIST_OFF / 4 + off + pos] = i;
}

// ---- phase 3: gather emb rows, fp32->bf16, store swizzled & bucket-contiguous ----
// one wave per sorted position p
__global__ void k_gather(const int* __restrict__ x,
                         const float* __restrict__ e0, const float* __restrict__ e1,
                         const float* __restrict__ e2, const float* __restrict__ e3,
                         char* __restrict__ ws) {
  int p = (blockIdx.x * 256 + threadIdx.x) >> 6;    // global wave id == sorted position
  int l = threadIdx.x & 63;
  const int* wsi = (const int*)ws;
  int c0 = wsi[0], c1 = wsi[1], c2 = wsi[2];
  int s1 = c0, s2 = c0 + c1, s3 = s2 + wsi[2];
  (void)c2;
  int b = (p >= s1) + (p >= s2) + (p >= s3);
  int cum = b == 0 ? 0 : b == 1 ? s1 : b == 2 ? s2 : s3;
  unsigned a0 = (unsigned)((c0 + 127) & ~127), a1 = (unsigned)((c1 + 127) & ~127),
           a2 = (unsigned)((wsi[2] + 127) & ~127);
  unsigned eoff = b == 0 ? 0u
                : b == 1 ? a0 * 2048u
                : b == 2 ? a0 * 2048u + a1 * 1024u
                         : a0 * 2048u + a1 * 1024u + a2 * 512u;

  int token = ((const int*)(ws + LIST_OFF))[p];
  int v = x[token];
  int d = EMB_DIM >> b;
  int lo = b == 0 ? 0 : b == 1 ? 300 : b == 2 ? 3000 : 30000;
  const float* eb = b == 0 ? e0 : b == 1 ? e1 : b == 2 ? e2 : e3;
  const float2* src = (const float2*)(eb + (size_t)(v - lo) * d);
  int rowInB = p - cum;
  char* dst = ws + EBF_OFF + (size_t)eoff + (size_t)rowInB * (unsigned)(2 * d);
  unsigned swz = ((unsigned)rowInB & 7u) << 4;
  int iters = d >> 7;
  for (int it = 0; it < iters; ++it) {
    int ci = l + (it << 6);                         // float2 index within row
    float2 f = src[ci];
    unsigned u = (unsigned)f2bf(f.x) | ((unsigned)f2bf(f.y) << 16);
    *(unsigned*)(dst + ((unsigned)(ci * 4) ^ swz)) = u;
  }
}

// ---- phase 4: W -> W^T bf16, swizzled ----
__global__ void k_wconv(const float* __restrict__ W0, const float* __restrict__ W1,
                        const float* __restrict__ W2, const float* __restrict__ W3,
                        char* __restrict__ ws) {
  int bid = blockIdx.x;
  int b, base;
  if (bid < 256)      { b = 0; base = 0; }
  else if (bid < 384) { b = 1; base = 256; }
  else if (bid < 448) { b = 2; base = 384; }
  else                { b = 3; base = 448; }
  int local = bid - base;
  int d = EMB_DIM >> b;
  int ktiles = d >> 6;
  int kt = local % ktiles, nt = local / ktiles;
  const float* W = b == 0 ? W0 : b == 1 ? W1 : b == 2 ? W2 : W3;
  char* wt = ws + WT_OFF + wt_base(b);
  __shared__ float tile[64][65];
  int tid = threadIdx.x;
  int tr = tid >> 6, tc = tid & 63;
#pragma unroll
  for (int it = 0; it < 16; ++it) {
    int kr = tr + (it << 2);
    tile[kr][tc] = W[(size_t)(kt * 64 + kr) * 1024 + (nt * 64 + tc)];
  }
  __syncthreads();
#pragma unroll
  for (int it = 0; it < 16; ++it) {
    int nl = tr + (it << 2);
    int n = nt * 64 + nl;
    unsigned short bv = f2bf(tile[tc][nl]);
    unsigned byte = ((unsigned)((kt * 64 + tc) * 2)) ^ (((unsigned)n & 7u) << 4);
    *(unsigned short*)(wt + (size_t)n * (unsigned)(2 * d) + byte) = bv;
  }
}

// ---- phase 5: per-bucket GEMM via MFMA ----
// grid (256 Mtiles, 8 Ntiles, 4 buckets), 256 threads, tile 128x128, K-chunks of 128
__launch_bounds__(256, 2)
__global__ void k_gemm(const char* __restrict__ ws, float* __restrict__ out) {
  const int b = blockIdx.z;
  const int* wsi = (const int*)ws;
  int cb = wsi[b];
  int m0 = blockIdx.x * 128;
  if (m0 >= cb) return;
  int n0 = blockIdx.y * 128;

  int cum = 0;
  unsigned eoff = 0;
  for (int j = 0; j < b; ++j) {
    int cj = wsi[j];
    cum += cj;
    eoff += (unsigned)((cj + 127) & ~127) * (unsigned)(2 * (EMB_DIM >> j));
  }
  const int d = EMB_DIM >> b;
  const unsigned rowB = (unsigned)(2 * d);
  const int nChunks = d >> 7;

  const char* ebf = ws + EBF_OFF + eoff;
  const char* wt = ws + WT_OFF + wt_base(b);
  const int* list = (const int*)(ws + LIST_OFF) + cum;

  __shared__ __align__(128) char smem[32768 * 2 + 512];
  char* sA = smem;
  char* sB = smem + 32768;
  int* tokl = (int*)(smem + 65536);

  int tid = threadIdx.x;
  int l = tid & 63, w = tid >> 6;
  int wm = w >> 1, wn = w & 1;
  int lane15 = l & 15, laneg = l >> 4;

  if (tid < 128) {
    int sp = m0 + tid;
    tokl[tid] = (sp < cb) ? list[sp] : -1;
  }

  f32x4 acc[4][4];
#pragma unroll
  for (int m = 0; m < 4; ++m)
#pragma unroll
    for (int n = 0; n < 4; ++n)
      acc[m][n] = (f32x4){0.f, 0.f, 0.f, 0.f};

  for (int kc = 0; kc < nChunks; ++kc) {
    if (kc) __syncthreads();
    // stage A tile [128 rows x 256B] and B tile, linear dest (data pre-swizzled)
#pragma unroll
    for (int it = 0; it < 8; ++it) {
      int idx = it * 256 + tid;
      int row = idx >> 4, slot = idx & 15;
      gload_lds16(ebf + (size_t)(m0 + row) * rowB + (unsigned)(kc * 256 + slot * 16),
                  sA + (it * 4096 + w * 1024));
    }
#pragma unroll
    for (int it = 0; it < 8; ++it) {
      int idx = it * 256 + tid;
      int row = idx >> 4, slot = idx & 15;
      gload_lds16(wt + (size_t)(n0 + row) * rowB + (unsigned)(kc * 256 + slot * 16),
                  sB + (it * 4096 + w * 1024));
    }
    __syncthreads();  // compiler emits vmcnt(0) drain before barrier

#pragma unroll
    for (int kk = 0; kk < 4; ++kk) {
      int kb = (kk << 6) + (laneg << 4);  // byte offset within 256B row-chunk
      short8 av[4], bv[4];
#pragma unroll
      for (int m = 0; m < 4; ++m) {
        int row = wm * 64 + m * 16 + lane15;
        av[m] = *(const short8*)(sA + row * 256 + (kb ^ ((row & 7) << 4)));
      }
#pragma unroll
      for (int n = 0; n < 4; ++n) {
        int col = wn * 64 + n * 16 + lane15;
        bv[n] = *(const short8*)(sB + col * 256 + (kb ^ ((col & 7) << 4)));
      }
#pragma unroll
      for (int m = 0; m < 4; ++m)
#pragma unroll
        for (int n = 0; n < 4; ++n)
          acc[m][n] = __builtin_amdgcn_mfma_f32_16x16x32_bf16(av[m], bv[n], acc[m][n], 0, 0, 0);
    }
  }

  // epilogue: scatter rows to out[token][col]; C/D map: col = l&15, row = 4*(l>>4)+j
#pragma unroll
  for (int m = 0; m < 4; ++m) {
    int rb = wm * 64 + m * 16 + laneg * 4;
#pragma unroll
    for (int j = 0; j < 4; ++j) {
      int tok = tokl[rb + j];
      if (tok >= 0) {
        float* orow = out + (size_t)tok * 1024 + n0 + wn * 64 + lane15;
#pragma unroll
        for (int n = 0; n < 4; ++n) orow[n * 16] = acc[m][n][j];
      }
    }
  }
}

extern "C" void kernel_launch(void* const* d_in, const int* in_sizes, int n_in,
                              void* d_out, int out_size, void* d_ws, size_t ws_size,
                              hipStream_t stream) {
  // resolve inputs by element count (all distinct) — immune to ordering assumptions
  const int* x = nullptr;
  const float *e0 = 0, *e1 = 0, *e2 = 0, *e3 = 0, *W0 = 0, *W1 = 0, *W2 = 0, *W3 = 0;
  for (int i = 0; i < n_in; ++i) {
    switch (in_sizes[i]) {
      case 32768:    x  = (const int*)d_in[i]; break;
      case 307200:   e0 = (const float*)d_in[i]; break;   // 300 x 1024
      case 1048576:  W0 = (const float*)d_in[i]; break;   // 1024 x 1024
      case 1382400:  e1 = (const float*)d_in[i]; break;   // 2700 x 512
      case 524288:   W1 = (const float*)d_in[i]; break;   // 512 x 1024
      case 6912000:  e2 = (const float*)d_in[i]; break;   // 27000 x 256
      case 262144:   W2 = (const float*)d_in[i]; break;   // 256 x 1024
      case 30429952: e3 = (const float*)d_in[i]; break;   // 237734 x 128
      case 131072:   W3 = (const float*)d_in[i]; break;   // 128 x 1024
    }
  }
  char* ws = (char*)d_ws;
  float* out = (float*)d_out;

  hipMemsetAsync(d_ws, 0, 32, stream);                       // counts + cursors
  k_count<<<128, 256, 0, stream>>>(x, (int*)ws);
  k_scatter<<<128, 256, 0, stream>>>(x, (int*)ws);
  k_gather<<<8192, 256, 0, stream>>>(x, e0, e1, e2, e3, ws); // 32768 waves
  k_wconv<<<480, 256, 0, stream>>>(W0, W1, W2, W3, ws);
  k_gemm<<<dim3(256, 8, 4), 256, 0, stream>>>(ws, out);
}

// Round 2
// 281.202 us; speedup vs baseline: 3.3441x; 3.3441x over previous
//
#include <hip/hip_runtime.h>

#define N_TOK   32768
#define EMB_DIM 1024

// ---- workspace layout (bytes) ----
// [0,16)      counts[4]
// [16,32)     cursors[4]
// [1024, +128KB)  sorted token index list (32768 ints), bucket-contiguous
// [256KB, +3.75MB) W^T bf16 (per-bucket, swizzled)
// [4MB, ...)  gathered emb rows bf16 (bucket-contiguous, rows padded to 128/bucket, swizzled)
#define LIST_OFF 1024u
#define WT_OFF   262144u
#define EBF_OFF  4194304u

typedef __attribute__((ext_vector_type(8))) short short8;
typedef __attribute__((ext_vector_type(4))) float f32x4;

__device__ __forceinline__ int bucket_of(int v) { return (v >= 300) + (v >= 3000) + (v >= 30000); }

__device__ __forceinline__ unsigned short f2bf(float f) {  // round-to-nearest-even fp32->bf16
  unsigned u = __float_as_uint(f);
  return (unsigned short)((u + 0x7FFFu + ((u >> 16) & 1u)) >> 16);
}

__device__ __forceinline__ unsigned wt_base(int b) {
  return b == 0 ? 0u : b == 1 ? 2097152u : b == 2 ? 3145728u : 3670016u;
}

__device__ __forceinline__ void gload_lds16(const void* g, void* l) {
  __builtin_amdgcn_global_load_lds((const __attribute__((address_space(1))) unsigned*)g,
                                   (__attribute__((address_space(3))) unsigned*)l, 16, 0, 0);
}

// ---- phase 1: histogram (per-block LDS aggregation -> 4 global atomics/block) ----
__global__ void k_count(const int* __restrict__ x, int* __restrict__ wsi) {
  __shared__ int lc[4];
  int tid = threadIdx.x;
  if (tid < 4) lc[tid] = 0;
  __syncthreads();
  int i = blockIdx.x * 256 + tid;                   // grid exact: 128*256 == N_TOK
  atomicAdd(&lc[bucket_of(x[i])], 1);
  __syncthreads();
  if (tid < 4 && lc[tid]) atomicAdd(&wsi[tid], lc[tid]);
}

// ---- phase 2: scatter token ids into bucket-contiguous list (aggregated atomics) ----
__global__ void k_scatter(const int* __restrict__ x, int* __restrict__ wsi) {
  __shared__ int lc[4], lb[4];
  int tid = threadIdx.x;
  if (tid < 4) lc[tid] = 0;
  __syncthreads();
  int i = blockIdx.x * 256 + tid;
  int v = x[i];
  int b = bucket_of(v);
  int posInBlk = atomicAdd(&lc[b], 1);              // LDS atomic: cheap
  __syncthreads();
  if (tid < 4) lb[tid] = lc[tid] ? atomicAdd(&wsi[4 + tid], lc[tid]) : 0;
  __syncthreads();
  int off = 0;
#pragma unroll
  for (int j = 0; j < 3; ++j) if (j < b) off += wsi[j];   // counts final (k_count done)
  wsi[LIST_OFF / 4 + off + lb[b] + posInBlk] = i;
}

// ---- phase 3: gather emb rows, fp32->bf16, store swizzled & bucket-contiguous ----
// one wave per sorted position p
__global__ void k_gather(const int* __restrict__ x,
                         const float* __restrict__ e0, const float* __restrict__ e1,
                         const float* __restrict__ e2, const float* __restrict__ e3,
                         char* __restrict__ ws) {
  int p = (blockIdx.x * 256 + threadIdx.x) >> 6;    // global wave id == sorted position
  int l = threadIdx.x & 63;
  const int* wsi = (const int*)ws;
  int c0 = wsi[0], c1 = wsi[1], c2 = wsi[2];
  int s1 = c0, s2 = c0 + c1, s3 = s2 + wsi[2];
  (void)c2;
  int b = (p >= s1) + (p >= s2) + (p >= s3);
  int cum = b == 0 ? 0 : b == 1 ? s1 : b == 2 ? s2 : s3;
  unsigned a0 = (unsigned)((c0 + 127) & ~127), a1 = (unsigned)((c1 + 127) & ~127),
           a2 = (unsigned)((wsi[2] + 127) & ~127);
  unsigned eoff = b == 0 ? 0u
                : b == 1 ? a0 * 2048u
                : b == 2 ? a0 * 2048u + a1 * 1024u
                         : a0 * 2048u + a1 * 1024u + a2 * 512u;

  int token = ((const int*)(ws + LIST_OFF))[p];
  int v = x[token];
  int d = EMB_DIM >> b;
  int lo = b == 0 ? 0 : b == 1 ? 300 : b == 2 ? 3000 : 30000;
  const float* eb = b == 0 ? e0 : b == 1 ? e1 : b == 2 ? e2 : e3;
  const float2* src = (const float2*)(eb + (size_t)(v - lo) * d);
  int rowInB = p - cum;
  char* dst = ws + EBF_OFF + (size_t)eoff + (size_t)rowInB * (unsigned)(2 * d);
  unsigned swz = ((unsigned)rowInB & 7u) << 4;
  int iters = d >> 7;
  for (int it = 0; it < iters; ++it) {
    int ci = l + (it << 6);                         // float2 index within row
    float2 f = src[ci];
    unsigned u = (unsigned)f2bf(f.x) | ((unsigned)f2bf(f.y) << 16);
    *(unsigned*)(dst + ((unsigned)(ci * 4) ^ swz)) = u;
  }
}

// ---- phase 4: W -> W^T bf16, swizzled ----
__global__ void k_wconv(const float* __restrict__ W0, const float* __restrict__ W1,
                        const float* __restrict__ W2, const float* __restrict__ W3,
                        char* __restrict__ ws) {
  int bid = blockIdx.x;
  int b, base;
  if (bid < 256)      { b = 0; base = 0; }
  else if (bid < 384) { b = 1; base = 256; }
  else if (bid < 448) { b = 2; base = 384; }
  else                { b = 3; base = 448; }
  int local = bid - base;
  int d = EMB_DIM >> b;
  int ktiles = d >> 6;
  int kt = local % ktiles, nt = local / ktiles;
  const float* W = b == 0 ? W0 : b == 1 ? W1 : b == 2 ? W2 : W3;
  char* wt = ws + WT_OFF + wt_base(b);
  __shared__ float tile[64][65];
  int tid = threadIdx.x;
  int tr = tid >> 6, tc = tid & 63;
#pragma unroll
  for (int it = 0; it < 16; ++it) {
    int kr = tr + (it << 2);
    tile[kr][tc] = W[(size_t)(kt * 64 + kr) * 1024 + (nt * 64 + tc)];
  }
  __syncthreads();
#pragma unroll
  for (int it = 0; it < 16; ++it) {
    int nl = tr + (it << 2);
    int n = nt * 64 + nl;
    unsigned short bv = f2bf(tile[tc][nl]);
    unsigned byte = ((unsigned)((kt * 64 + tc) * 2)) ^ (((unsigned)n & 7u) << 4);
    *(unsigned short*)(wt + (size_t)n * (unsigned)(2 * d) + byte) = bv;
  }
}

// ---- phase 5: per-bucket GEMM via MFMA ----
// grid (256 Mtiles, 8 Ntiles, 4 buckets), 256 threads, tile 128x128, K-chunks of 128
__launch_bounds__(256, 2)
__global__ void k_gemm(const char* __restrict__ ws, float* __restrict__ out) {
  const int b = blockIdx.z;
  const int* wsi = (const int*)ws;
  int cb = wsi[b];
  int m0 = blockIdx.x * 128;
  if (m0 >= cb) return;
  int n0 = blockIdx.y * 128;

  int cum = 0;
  unsigned eoff = 0;
  for (int j = 0; j < b; ++j) {
    int cj = wsi[j];
    cum += cj;
    eoff += (unsigned)((cj + 127) & ~127) * (unsigned)(2 * (EMB_DIM >> j));
  }
  const int d = EMB_DIM >> b;
  const unsigned rowB = (unsigned)(2 * d);
  const int nChunks = d >> 7;

  const char* ebf = ws + EBF_OFF + eoff;
  const char* wt = ws + WT_OFF + wt_base(b);
  const int* list = (const int*)(ws + LIST_OFF) + cum;

  __shared__ __align__(128) char smem[32768 * 2 + 512];
  char* sA = smem;
  char* sB = smem + 32768;
  int* tokl = (int*)(smem + 65536);

  int tid = threadIdx.x;
  int l = tid & 63, w = tid >> 6;
  int wm = w >> 1, wn = w & 1;
  int lane15 = l & 15, laneg = l >> 4;

  if (tid < 128) {
    int sp = m0 + tid;
    tokl[tid] = (sp < cb) ? list[sp] : -1;
  }

  f32x4 acc[4][4];
#pragma unroll
  for (int m = 0; m < 4; ++m)
#pragma unroll
    for (int n = 0; n < 4; ++n)
      acc[m][n] = (f32x4){0.f, 0.f, 0.f, 0.f};

  for (int kc = 0; kc < nChunks; ++kc) {
    if (kc) __syncthreads();
    // stage A tile [128 rows x 256B] and B tile, linear dest (data pre-swizzled)
#pragma unroll
    for (int it = 0; it < 8; ++it) {
      int idx = it * 256 + tid;
      int row = idx >> 4, slot = idx & 15;
      gload_lds16(ebf + (size_t)(m0 + row) * rowB + (unsigned)(kc * 256 + slot * 16),
                  sA + (it * 4096 + w * 1024));
    }
#pragma unroll
    for (int it = 0; it < 8; ++it) {
      int idx = it * 256 + tid;
      int row = idx >> 4, slot = idx & 15;
      gload_lds16(wt + (size_t)(n0 + row) * rowB + (unsigned)(kc * 256 + slot * 16),
                  sB + (it * 4096 + w * 1024));
    }
    __syncthreads();  // compiler emits vmcnt(0) drain before barrier

#pragma unroll
    for (int kk = 0; kk < 4; ++kk) {
      int kb = (kk << 6) + (laneg << 4);  // byte offset within 256B row-chunk
      short8 av[4], bv[4];
#pragma unroll
      for (int m = 0; m < 4; ++m) {
        int row = wm * 64 + m * 16 + lane15;
        av[m] = *(const short8*)(sA + row * 256 + (kb ^ ((row & 7) << 4)));
      }
#pragma unroll
      for (int n = 0; n < 4; ++n) {
        int col = wn * 64 + n * 16 + lane15;
        bv[n] = *(const short8*)(sB + col * 256 + (kb ^ ((col & 7) << 4)));
      }
#pragma unroll
      for (int m = 0; m < 4; ++m)
#pragma unroll
        for (int n = 0; n < 4; ++n)
          acc[m][n] = __builtin_amdgcn_mfma_f32_16x16x32_bf16(av[m], bv[n], acc[m][n], 0, 0, 0);
    }
  }

  // epilogue: scatter rows to out[token][col]; C/D map: col = l&15, row = 4*(l>>4)+j
#pragma unroll
  for (int m = 0; m < 4; ++m) {
    int rb = wm * 64 + m * 16 + laneg * 4;
#pragma unroll
    for (int j = 0; j < 4; ++j) {
      int tok = tokl[rb + j];
      if (tok >= 0) {
        float* orow = out + (size_t)tok * 1024 + n0 + wn * 64 + lane15;
#pragma unroll
        for (int n = 0; n < 4; ++n) orow[n * 16] = acc[m][n][j];
      }
    }
  }
}

extern "C" void kernel_launch(void* const* d_in, const int* in_sizes, int n_in,
                              void* d_out, int out_size, void* d_ws, size_t ws_size,
                              hipStream_t stream) {
  // resolve inputs by element count (all distinct) — immune to ordering assumptions
  const int* x = nullptr;
  const float *e0 = 0, *e1 = 0, *e2 = 0, *e3 = 0, *W0 = 0, *W1 = 0, *W2 = 0, *W3 = 0;
  for (int i = 0; i < n_in; ++i) {
    switch (in_sizes[i]) {
      case 32768:    x  = (const int*)d_in[i]; break;
      case 307200:   e0 = (const float*)d_in[i]; break;   // 300 x 1024
      case 1048576:  W0 = (const float*)d_in[i]; break;   // 1024 x 1024
      case 1382400:  e1 = (const float*)d_in[i]; break;   // 2700 x 512
      case 524288:   W1 = (const float*)d_in[i]; break;   // 512 x 1024
      case 6912000:  e2 = (const float*)d_in[i]; break;   // 27000 x 256
      case 262144:   W2 = (const float*)d_in[i]; break;   // 256 x 1024
      case 30429952: e3 = (const float*)d_in[i]; break;   // 237734 x 128
      case 131072:   W3 = (const float*)d_in[i]; break;   // 128 x 1024
    }
  }
  char* ws = (char*)d_ws;
  float* out = (float*)d_out;

  hipMemsetAsync(d_ws, 0, 32, stream);                       // counts + cursors
  k_count<<<128, 256, 0, stream>>>(x, (int*)ws);
  k_scatter<<<128, 256, 0, stream>>>(x, (int*)ws);
  k_gather<<<8192, 256, 0, stream>>>(x, e0, e1, e2, e3, ws); // 32768 waves
  k_wconv<<<480, 256, 0, stream>>>(W0, W1, W2, W3, ws);
  k_gemm<<<dim3(256, 8, 4), 256, 0, stream>>>(ws, out);
}